// Round 14
// baseline (622.966 us; speedup 1.0000x reference)
//
#include <hip/hip_runtime.h>

typedef _Float16 half8 __attribute__((ext_vector_type(8)));
typedef _Float16 half2v __attribute__((ext_vector_type(2)));
typedef float floatx4 __attribute__((ext_vector_type(4)));

#define DEVI __device__ __forceinline__
#define AS1 __attribute__((address_space(1)))
#define AS3 __attribute__((address_space(3)))
#define GLL(gp, lp) __builtin_amdgcn_global_load_lds((const AS1 void*)(gp), (AS3 void*)(lp), 16, 0, 0)
#define VM0 asm volatile("s_waitcnt vmcnt(0)" ::: "memory")
#define BAR __builtin_amdgcn_s_barrier()
#define MFMA16(a, b, c) __builtin_amdgcn_mfma_f32_16x16x32_f16(a, b, c, 0, 0, 0)

namespace {
constexpr int C_   = 256;
constexpr int DHW_ = 8192;
constexpr int N_   = 16384;   // rows = B*D*H*W
constexpr int NE_  = 8192;    // codebook entries
constexpr int K_   = 256;     // embedding dim

constexpr size_t LOSS_OFF  = 4194304;
constexpr size_t PERP_OFF  = 4194305;
constexpr size_t ENC_OFF   = 4194306;
constexpr size_t ENC_N     = 134217728ull;
constexpr size_t IDX_OFF   = ENC_OFF + ENC_N;

// scratch offsets from 256B-aligned base inside enc-region tail
// (everything consumed before vq_zero_tail wipes it; all >= TAIL_START)
constexpr size_t SCR_WL   = 472ull << 20;               // wl[row*64+slot] u32 = 4 MiB
constexpr size_t SCR_LMIN = 476ull << 20;               // 64 x 16384 u32 = 4 MiB
constexpr size_t SCR_ZH   = 480ull << 20;  // blocked 16384x256 f16 = 8 MiB
constexpr size_t SCR_ZL   = 488ull << 20;
constexpr size_t SCR_EH   = 496ull << 20;  // blocked 8192x256 f16 = 4 MiB
constexpr size_t SCR_EL   = 500ull << 20;
constexpr size_t SCR_ZZ   = 504ull << 20;               // 16384 f32
constexpr size_t SCR_R    = (504ull << 20) + 65536;     // 16384 f32 cross-bound
constexpr size_t SCR_GMIN = (504ull << 20) + 131072;    // 16384 u32 global approx min
constexpr size_t SCR_WCNT = (504ull << 20) + 196608;    // 16384 u32 per-row counts (64KB)
constexpr size_t SCR_KEY  = 505ull << 20;  // 16384 u64
constexpr size_t SCR_PART = 506ull << 20;  // loss partials f32
constexpr size_t SCR_HIST = 507ull << 20;  // 8192 i32

constexpr int NLOSS_BLOCKS = 2048;

constexpr float S_A = 1.0f / 65536.0f;       // 2^-16
constexpr float S_B = 1.0f / 134217728.0f;   // 2^-27

// enc zero-fill: 8192 K2 blocks NT-store 56KB each starting at encb+8.
constexpr size_t ZFILL_PER_BLK = 57344;                       // 14 x 4KB rounds
constexpr size_t TAIL_START    = 8 + 8192ull * ZFILL_PER_BLK; // 469762056
constexpr size_t TAIL_F4       = (536870904ull - TAIL_START) / 16;  // 4194303
}

// Blocked layouts (staging contiguous 16B/lane; LDS conflict-free):
//   A (Z): bytes = tile256*131072 + chunk*16384 + oct*4096 + row*16 + (k&7)*2
//   B (E): bytes = tile128*65536  + chunk*8192  + oct*2048 + col*16 + (k&7)*2

// ---------------- fused split: blocked f16 splits + zz + cross-bound R + inits ----------------
__global__ void vq_split(const float* __restrict__ z, const float* __restrict__ cb,
                         _Float16* __restrict__ ZHb, _Float16* __restrict__ ZLb,
                         _Float16* __restrict__ EHb, _Float16* __restrict__ ELb,
                         float* __restrict__ zz, float* __restrict__ Rr,
                         unsigned long long* __restrict__ keys, int* __restrict__ hist,
                         unsigned* __restrict__ gmin, unsigned* __restrict__ wcnt) {
    __shared__ float tile[64][260];
    __shared__ float sab[32][8];
    int t = threadIdx.x;
    if (blockIdx.x < 512) {
        // ---- Z path: rows n0..n0+31 ----
        int n0 = blockIdx.x * 32;
        int b  = n0 >> 13;
        int d0 = n0 & 8191;
        const float* zb = z + (size_t)b * (C_ * DHW_) + d0;
        int j5 = t & 31, cg8 = t >> 5;          // 8 c-groups
        for (int cc = 0; cc < 256; cc += 8) {
            int c = cc + cg8;
            tile[j5][c] = zb[(size_t)c * DHW_ + j5];   // coalesced over j5
        }
        __syncthreads();
        int tl = n0 >> 8, r0 = n0 & 255;
        float acc = 0.f;                         // Sum(|zh|+|zl|) partial (for R)
        #pragma unroll
        for (int it = 0; it < 4; ++it) {
            int rid = it * 8 + cg8;                    // k-octet 0..31
            half8 h, l;
            #pragma unroll
            for (int e = 0; e < 8; ++e) {
                float v = tile[j5][rid * 8 + e];
                _Float16 hh = (_Float16)v;
                float lf = (v - (float)hh) * 2048.0f;  // residual scaled 2^11
                h[e] = hh;
                l[e] = (_Float16)lf;
                acc += fabsf((float)hh) + fabsf((float)(_Float16)lf);
            }
            size_t off = ((size_t)(tl * 8 + (rid >> 2))) * 8192
                       + (size_t)(rid & 3) * 2048 + (size_t)(r0 + j5) * 8;
            *(half8*)(ZHb + off) = h;
            *(half8*)(ZLb + off) = l;
        }
        sab[j5][cg8] = acc;
        __syncthreads();
        // zz (same per-row math as the passing rounds; only binade matters)
        if (t < 32) {
            float tot[2];
            for (int h2 = 0; h2 < 2; ++h2) {
                float r8[8];
                #pragma unroll
                for (int k = 0; k < 8; ++k) { float x = tile[t][h2*128 + k]; r8[k] = x * x; }
                for (int i = 8; i < 128; i += 8) {
                    #pragma unroll
                    for (int k = 0; k < 8; ++k) { float x = tile[t][h2*128 + i + k]; r8[k] += x * x; }
                }
                tot[h2] = ((r8[0]+r8[1]) + (r8[2]+r8[3])) + ((r8[4]+r8[5]) + (r8[6]+r8[7]));
            }
            zz[n0 + t] = tot[0] + tot[1];
            float s = 0.f;
            #pragma unroll
            for (int gq = 0; gq < 8; ++gq) s += sab[t][gq];
            // hard bound on 2*S_B*|cross|: |eh|<=8.004, |el|<=8  -> 8.01 covers
            Rr[n0 + t] = s * (2.0f * 8.01f / 134217728.0f);
        }
        if (blockIdx.x < 64) keys[blockIdx.x * 256 + t] = ~0ull;
        else if (blockIdx.x < 96) hist[(blockIdx.x - 64) * 256 + t] = 0;
        else if (blockIdx.x < 160) gmin[(blockIdx.x - 96) * 256 + t] = 0xFFFFFFFFu;
        else if (blockIdx.x < 224) wcnt[(blockIdx.x - 160) * 256 + t] = 0u;
    } else {
        // ---- E path: codebook rows j0..j0+63, pre-scaled by 2^16 (exact) ----
        int j = t & 63, grp = t >> 6;
        int j0 = (blockIdx.x - 512) * 64;
        for (int i = 0; i < 64; ++i)
            tile[i][t] = cb[(size_t)(j0 + i) * K_ + t] * 65536.0f;   // coalesced over t
        __syncthreads();
        int tl = j0 >> 7, r0 = j0 & 127;
        #pragma unroll
        for (int it = 0; it < 8; ++it) {
            int rid = it * 4 + grp;
            half8 h, l;
            #pragma unroll
            for (int e = 0; e < 8; ++e) {
                float v = tile[j][rid * 8 + e];
                _Float16 hh = (_Float16)v;
                h[e] = hh;
                l[e] = (_Float16)((v - (float)hh) * 2048.0f);
            }
            size_t off = ((size_t)(tl * 8 + (rid >> 2))) * 4096
                       + (size_t)(rid & 3) * 1024 + (size_t)(r0 + j) * 8;
            *(half8*)(EHb + off) = h;
            *(half8*)(ELb + off) = l;
        }
    }
}

// ---------------- K2: pass-A GEMM -> per-(row,block) local min + global min + zfill ----------------
// TM=TN=128, KC=32, 8 chunks, 4 waves (2x2), 2 bufs x 16KB (ZH+EH) -> 4 blocks/CU.

DEVI void stage_chunk(const char* zh, const char* eh, char* b, int t, int c) {
    #pragma unroll
    for (int i = 0; i < 2; ++i) {
        int f = i * 256 + t;                       // 0..511 = oct*128 + row
        int ao = (f >> 7) * 4096 + (f & 127) * 16;
        GLL(zh + (size_t)c * 16384 + ao, b + f * 16);
    }
    #pragma unroll
    for (int i = 0; i < 2; ++i) {
        int f = i * 256 + t;
        int eo = (f >> 7) * 2048 + (f & 127) * 16;
        GLL(eh + (size_t)c * 8192 + eo, b + 8192 + f * 16);
    }
}

DEVI void zfill2(char* zb, int t, int r0) {
    floatx4 z4 = {0.f, 0.f, 0.f, 0.f};
    __builtin_nontemporal_store(z4, (floatx4*)(zb + (size_t)r0 * 4096 + t * 16));
    __builtin_nontemporal_store(z4, (floatx4*)(zb + (size_t)(r0 + 1) * 4096 + t * 16));
}

DEVI void compute_chunk(const char* b, int wm, int wn, int rr,
                        floatx4 (&acc)[4][4]) {
    const char* Ab = b;
    const char* Bb = b + 8192;
    half8 azh[4], beh[4];
    #pragma unroll
    for (int f = 0; f < 4; ++f) {
        int row = wm * 64 + f * 16 + rr;
        azh[f] = *(const half8*)(Ab + row * 16);
        int col = wn * 64 + f * 16 + rr;
        beh[f] = *(const half8*)(Bb + col * 16);
    }
    __builtin_amdgcn_s_setprio(1);
    #pragma unroll
    for (int fi = 0; fi < 4; ++fi)
        #pragma unroll
        for (int fj = 0; fj < 4; ++fj)
            acc[fi][fj] = MFMA16(azh[fi], beh[fj], acc[fi][fj]);
    __builtin_amdgcn_s_setprio(0);
}

__launch_bounds__(256, 4)
__global__ void vq_gemm1(const _Float16* __restrict__ ZHb, const _Float16* __restrict__ EHb,
                         const float* __restrict__ zz,
                         unsigned* __restrict__ Lmin, unsigned* __restrict__ gmin,
                         char* __restrict__ zfill) {
    __shared__ _Float16 lds[2][8192];                 // 2 x 16KB (ZH+EH only)
    __shared__ unsigned rowminu[128];

    int orig = blockIdx.x;
    int xcd = orig & 7;
    int loc = orig >> 3;                 // 0..1023
    int bm = xcd * 16 + (loc & 15);      // 0..127 (128-row Z slices)
    int bn = loc >> 4;                   // 0..63  (128-row E tiles)
    int m0 = bm * 128;

    int t = threadIdx.x;
    int lane = t & 63, wid = t >> 6;
    int wm = wid >> 1, wn = wid & 1;     // 2x2 waves of 64x64
    int g = lane >> 4, rr = lane & 15;

    const char* zh = (const char*)ZHb + (size_t)(bm >> 1) * 131072 + (size_t)(bm & 1) * 2048;
    const char* eh = (const char*)EHb + (size_t)bn * 65536;
    char* zb = zfill + (size_t)orig * ZFILL_PER_BLK;

    floatx4 acc[4][4];
    #pragma unroll
    for (int i = 0; i < 4; ++i)
        #pragma unroll
        for (int jj = 0; jj < 4; ++jj)
            acc[i][jj] = (floatx4){0.f, 0.f, 0.f, 0.f};

    char* L0 = (char*)lds[0];
    char* L1 = (char*)lds[1];
    char* L0g = L0 + g * 2048;
    char* L1g = L1 + g * 2048;

    stage_chunk(zh, eh, L0, t, 0);
    VM0; BAR;
    stage_chunk(zh, eh, L1, t, 1); zfill2(zb, t, 0);  compute_chunk(L0g, wm, wn, rr, acc); VM0; BAR;
    stage_chunk(zh, eh, L0, t, 2); zfill2(zb, t, 2);  compute_chunk(L1g, wm, wn, rr, acc); VM0; BAR;
    stage_chunk(zh, eh, L1, t, 3); zfill2(zb, t, 4);  compute_chunk(L0g, wm, wn, rr, acc); VM0; BAR;
    stage_chunk(zh, eh, L0, t, 4); zfill2(zb, t, 6);  compute_chunk(L1g, wm, wn, rr, acc); VM0; BAR;
    stage_chunk(zh, eh, L1, t, 5); zfill2(zb, t, 8);  compute_chunk(L0g, wm, wn, rr, acc); VM0; BAR;
    stage_chunk(zh, eh, L0, t, 6); zfill2(zb, t, 10); compute_chunk(L1g, wm, wn, rr, acc); VM0; BAR;
    stage_chunk(zh, eh, L1, t, 7); zfill2(zb, t, 12); compute_chunk(L0g, wm, wn, rr, acc); VM0; BAR;
    compute_chunk(L1g, wm, wn, rr, acc);

    if (t < 128) rowminu[t] = 0xFFFFFFFFu;
    __syncthreads();
    #pragma unroll
    for (int fi = 0; fi < 4; ++fi) {
        #pragma unroll
        for (int r = 0; r < 4; ++r) {
            int rowl = wm * 64 + fi * 16 + g * 4 + r;
            float zzv = zz[m0 + rowl];
            unsigned best = 0xFFFFFFFFu;
            #pragma unroll
            for (int fj = 0; fj < 4; ++fj) {
                float d = zzv - 2.0f * (acc[fi][fj][r] * S_A);   // approx (pass-A), d>0
                unsigned db = __float_as_uint(d);
                if (db < best) best = db;
            }
            #pragma unroll
            for (int s = 1; s < 16; s <<= 1) {
                unsigned o = __shfl_xor(best, s, 64);
                if (o < best) best = o;
            }
            if (rr == 0) atomicMin(&rowminu[rowl], best);
        }
    }
    __syncthreads();
    if (t < 128) {
        unsigned v = rowminu[t];
        Lmin[(size_t)bn * 16384 + m0 + t] = v;
        atomicMin(&gmin[m0 + t], v);
    }
}

// ---------------- K3a: scan Lmin -> per-row worklists (contention-free atomics) ----------------
__global__ void vq_scan(const unsigned* __restrict__ Lmin, const unsigned* __restrict__ gmin,
                        const float* __restrict__ Rr,
                        unsigned* __restrict__ wl, unsigned* __restrict__ wcnt) {
    int idx = blockIdx.x * 256 + threadIdx.x;     // bn*16384 + row
    int row = idx & 16383;
    int bn = idx >> 14;
    float thr = __uint_as_float(gmin[row]) + 2.0f * Rr[row] + 2e-4f;
    if (__uint_as_float(Lmin[idx]) <= thr) {
        unsigned slot = atomicAdd(&wcnt[row], 1u);   // 16384 counters -> no contention
        wl[(size_t)row * 64 + slot] = (unsigned)bn;  // <=64 blocks/row, no overflow
    }
}

// ---------------- K3b: wave-per-row exact refine ----------------
// Each wave owns rows (grid-stride); per hot block: approx filter (128 coalesced
// col-dots), survivors evaluated wave-parallel; atomicMin exact key (per-row).

DEVI float dot8f(half8 a, half8 b, float c) {
#if __has_builtin(__builtin_amdgcn_fdot2)
    const half2v* pa = (const half2v*)&a;
    const half2v* pb = (const half2v*)&b;
    c = __builtin_amdgcn_fdot2(pa[0], pb[0], c, false);
    c = __builtin_amdgcn_fdot2(pa[1], pb[1], c, false);
    c = __builtin_amdgcn_fdot2(pa[2], pb[2], c, false);
    c = __builtin_amdgcn_fdot2(pa[3], pb[3], c, false);
#else
    #pragma unroll
    for (int q = 0; q < 8; ++q) c += (float)a[q] * (float)b[q];
#endif
    return c;
}

__launch_bounds__(256, 4)
__global__ void vq_refine(const _Float16* __restrict__ ZHb, const _Float16* __restrict__ ZLb,
                          const _Float16* __restrict__ EHb, const _Float16* __restrict__ ELb,
                          const float* __restrict__ zz, const float* __restrict__ Rr,
                          const unsigned* __restrict__ gmin,
                          const unsigned* __restrict__ wl, const unsigned* __restrict__ wcnt,
                          unsigned long long* __restrict__ keys) {
    int t = threadIdx.x;
    int lane = t & 63;
    int gw = blockIdx.x * 4 + (t >> 6);     // global wave id (8192 waves)
    for (int row = gw; row < N_; row += 8192) {
        int nh = (int)wcnt[row];
        const char* zhr = (const char*)ZHb + (size_t)(row >> 8) * 131072 + (size_t)(row & 255) * 16;
        const char* zlr = (const char*)ZLb + (size_t)(row >> 8) * 131072 + (size_t)(row & 255) * 16;
        float zzv = zz[row];
        float thr = __uint_as_float(gmin[row]) + 2.0f * Rr[row] + 2e-4f;
        for (int h = 0; h < nh; ++h) {
            int bn = (int)wl[(size_t)row * 64 + h];
            const char* ehb = (const char*)EHb + (size_t)bn * 65536;
            const char* elb = (const char*)ELb + (size_t)bn * 65536;
            #pragma unroll
            for (int half = 0; half < 2; ++half) {
                int j = half * 64 + lane;
                const char* ehc = ehb + (size_t)j * 16;
                float acc = 0.f;
                #pragma unroll
                for (int oc = 0; oc < 32; ++oc) {
                    size_t ao = (size_t)(oc >> 2) * 16384 + (size_t)(oc & 3) * 4096;
                    size_t eo = (size_t)(oc >> 2) * 8192 + (size_t)(oc & 3) * 2048;
                    half8 zh8 = *(const half8*)(zhr + ao);     // wave-uniform (broadcast)
                    half8 eh8 = *(const half8*)(ehc + eo);     // coalesced across lanes
                    acc = dot8f(zh8, eh8, acc);                // filter only (2e-4 pad)
                }
                float da = zzv - 2.0f * (acc * S_A);
                unsigned long long mask = __ballot(da <= thr);
                while (mask) {
                    int b = __ffsll((unsigned long long)mask) - 1;
                    mask &= mask - 1;
                    int jc = half * 64 + b;
                    // wave-parallel exact eval (validated formula class)
                    int oc = lane & 31;
                    size_t ao = (size_t)(oc >> 2) * 16384 + (size_t)(oc & 3) * 4096;
                    size_t eo = (size_t)(oc >> 2) * 8192 + (size_t)(oc & 3) * 2048;
                    const char* ecc = ehb + (size_t)jc * 16;
                    const char* elc = elb + (size_t)jc * 16;
                    half8 zh8 = *(const half8*)(zhr + ao);
                    half8 eh8 = *(const half8*)(ecc + eo);
                    float part = 0.f;
                    if (lane < 32) {
                        #pragma unroll
                        for (int q = 0; q < 8; ++q)
                            part += (float)zh8[q] * (float)eh8[q];
                    } else {
                        half8 zl8 = *(const half8*)(zlr + ao);
                        half8 el8 = *(const half8*)(elc + eo);
                        #pragma unroll
                        for (int q = 0; q < 8; ++q)
                            part += (float)zl8[q] * (float)eh8[q] + (float)zh8[q] * (float)el8[q];
                    }
                    #pragma unroll
                    for (int s = 1; s < 32; s <<= 1) part += __shfl_xor(part, s, 64);
                    float other = __shfl_xor(part, 32, 64);
                    if (lane == 0) {
                        float dot = part * S_A + other * S_B;   // ah*S_A + cross*S_B
                        float d = zzv - 2.0f * dot;
                        unsigned long long key = ((unsigned long long)__float_as_uint(d) << 32)
                                               | (unsigned)(bn * 128 + jc);
                        atomicMin(&keys[row], key);
                    }
                }
            }
        }
    }
}

// ---------------- z_q + loss partials + idx output + histogram (fused) ----------------
__global__ void vq_zq_loss(const float* __restrict__ z, const float* __restrict__ cb,
                           const unsigned long long* __restrict__ keys,
                           float* __restrict__ out0, float* __restrict__ parts,
                           float* __restrict__ out_idx, int* __restrict__ hist) {
    size_t i0 = ((size_t)blockIdx.x * 256 + threadIdx.x) * 8;
    int c   = (int)((i0 >> 13) & 255);
    int b   = (int)(i0 >> 21);
    int dhw = (int)(i0 & 8191);
    int nb  = b * DHW_ + dhw;
    int jj[8];
    #pragma unroll
    for (int e = 0; e < 8; ++e)
        jj[e] = (int)(unsigned)(keys[nb + e] & 0xFFFFFFFFull);
    float ls = 0.f;
    #pragma unroll
    for (int e = 0; e < 8; ++e) {
        float zq = cb[(size_t)jj[e] * K_ + c];
        float zt = z[i0 + e];
        float diff = zq - zt;        // fl, matches ref
        out0[i0 + e] = zt + diff;    // fl(z_t + fl(z_q - z_t))
        ls += diff * diff;
    }
    if (c == 0) {
        #pragma unroll
        for (int e = 0; e < 8; ++e) {
            out_idx[nb + e] = (float)jj[e];
            atomicAdd(&hist[jj[e]], 1);
        }
    }
    __shared__ float red[256];
    red[threadIdx.x] = ls;
    __syncthreads();
    for (int s = 128; s > 0; s >>= 1) {
        if (threadIdx.x < (unsigned)s) red[threadIdx.x] += red[threadIdx.x + s];
        __syncthreads();
    }
    if (threadIdx.x == 0) parts[blockIdx.x] = red[0];
}

// ---------------- loss + perplexity ----------------
__global__ void vq_finalize_scalars(const float* __restrict__ parts,
                                    const int* __restrict__ hist,
                                    float* __restrict__ out) {
    __shared__ double dred[256];
    int t = threadIdx.x;
    double ent = 0.0;
    for (int i = t; i < NE_; i += 256) {
        float em = (float)hist[i] * (1.0f / 16384.0f);   // exact (pow2)
        float term = em * logf(em + 1e-10f);
        ent += (double)term;
    }
    dred[t] = ent;
    __syncthreads();
    for (int s = 128; s > 0; s >>= 1) {
        if (t < s) dred[t] += dred[t + s];
        __syncthreads();
    }
    double entr = 0.0;
    if (t == 0) entr = dred[0];
    __syncthreads();
    double ls = 0.0;
    for (int i = t; i < NLOSS_BLOCKS; i += 256) ls += (double)parts[i];
    dred[t] = ls;
    __syncthreads();
    for (int s = 128; s > 0; s >>= 1) {
        if (t < s) dred[t] += dred[t + s];
        __syncthreads();
    }
    if (t == 0) {
        double m = dred[0] / 4194304.0;
        float m1 = (float)m;
        out[LOSS_OFF] = m1 + 0.25f * m1;
        out[PERP_OFF] = (float)exp(-entr);
    }
}

// ---------------- zero the scratch tail + head/tail slivers of enc ----------------
__global__ void vq_zero_tail(char* __restrict__ encb) {
    size_t i = (size_t)blockIdx.x * 256 + threadIdx.x;
    floatx4 z4 = {0.f, 0.f, 0.f, 0.f};
    char* base = encb + TAIL_START;
    for (size_t k = i; k < TAIL_F4; k += 131072)
        *(floatx4*)(base + k * 16) = z4;
    if (i == 0) {
        float2 z2 = {0.f, 0.f};
        *(float2*)encb = z2;                      // enc[0..1]
        *(float2*)(encb + 536870904ull) = z2;     // enc[last two]
    }
}

// ---------------- place the ones ----------------
__global__ void vq_write_ones(const float* __restrict__ idxf, float* __restrict__ enc) {
    int n = blockIdx.x * 256 + threadIdx.x;
    enc[(size_t)n * NE_ + (int)idxf[n]] = 1.0f;
}

extern "C" void kernel_launch(void* const* d_in, const int* in_sizes, int n_in,
                              void* d_out, int out_size, void* d_ws, size_t ws_size,
                              hipStream_t stream) {
    const float* z  = (const float*)d_in[0];
    const float* cb = (const float*)d_in[1];
    float* out = (float*)d_out;

    // 256B-aligned scratch base inside the enc-region tail
    char* scr = (char*)(((uintptr_t)(out + ENC_OFF) + 255) & ~(uintptr_t)255);
    _Float16* ZHb = (_Float16*)(scr + SCR_ZH);
    _Float16* ZLb = (_Float16*)(scr + SCR_ZL);
    _Float16* EHb = (_Float16*)(scr + SCR_EH);
    _Float16* ELb = (_Float16*)(scr + SCR_EL);
    float* zz = (float*)(scr + SCR_ZZ);
    float* Rr = (float*)(scr + SCR_R);
    unsigned* gmin = (unsigned*)(scr + SCR_GMIN);
    unsigned* wcnt = (unsigned*)(scr + SCR_WCNT);
    unsigned* Lmin = (unsigned*)(scr + SCR_LMIN);
    unsigned* wl = (unsigned*)(scr + SCR_WL);
    unsigned long long* keys = (unsigned long long*)(scr + SCR_KEY);
    float* parts = (float*)(scr + SCR_PART);
    int* hist = (int*)(scr + SCR_HIST);
    float* out_idx = out + IDX_OFF;
    float* enc = out + ENC_OFF;
    char* encb = (char*)enc;

    vq_split<<<640, 256, 0, stream>>>(z, cb, ZHb, ZLb, EHb, ELb, zz, Rr, keys, hist, gmin, wcnt);
    vq_gemm1<<<8192, 256, 0, stream>>>(ZHb, EHb, zz, Lmin, gmin, encb + 8);
    vq_scan<<<4096, 256, 0, stream>>>(Lmin, gmin, Rr, wl, wcnt);
    vq_refine<<<2048, 256, 0, stream>>>(ZHb, ZLb, EHb, ELb, zz, Rr, gmin, wl, wcnt, keys);
    vq_zq_loss<<<NLOSS_BLOCKS, 256, 0, stream>>>(z, cb, keys, out, parts, out_idx, hist);
    vq_finalize_scalars<<<1, 256, 0, stream>>>(parts, hist, out);
    vq_zero_tail<<<512, 256, 0, stream>>>(encb);
    vq_write_ones<<<64, 256, 0, stream>>>(out_idx, enc);
}

// Round 15
// 263.473 us; speedup vs baseline: 2.3644x; 2.3644x over previous
//
#include <hip/hip_runtime.h>

typedef _Float16 half8 __attribute__((ext_vector_type(8)));
typedef _Float16 half2v __attribute__((ext_vector_type(2)));
typedef float floatx4 __attribute__((ext_vector_type(4)));

#define DEVI __device__ __forceinline__
#define AS1 __attribute__((address_space(1)))
#define AS3 __attribute__((address_space(3)))
#define GLL(gp, lp) __builtin_amdgcn_global_load_lds((const AS1 void*)(gp), (AS3 void*)(lp), 16, 0, 0)
#define VM0 asm volatile("s_waitcnt vmcnt(0)" ::: "memory")
#define BAR __builtin_amdgcn_s_barrier()
#define MFMA16(a, b, c) __builtin_amdgcn_mfma_f32_16x16x32_f16(a, b, c, 0, 0, 0)

namespace {
constexpr int C_   = 256;
constexpr int DHW_ = 8192;
constexpr int N_   = 16384;   // rows = B*D*H*W
constexpr int NE_  = 8192;    // codebook entries
constexpr int K_   = 256;     // embedding dim

constexpr size_t LOSS_OFF  = 4194304;
constexpr size_t PERP_OFF  = 4194305;
constexpr size_t ENC_OFF   = 4194306;
constexpr size_t ENC_N     = 134217728ull;
constexpr size_t IDX_OFF   = ENC_OFF + ENC_N;

// scratch offsets from 256B-aligned base inside enc-region tail
// (everything consumed before vq_zero_tail wipes it; all >= TAIL_START)
constexpr size_t SCR_CAND = 449ull << 20;  // cand[row*CAP+slot] u64 = 21 MiB
constexpr size_t SCR_ZH   = 480ull << 20;  // blocked 16384x256 f16 = 8 MiB
constexpr size_t SCR_ZL   = 488ull << 20;
constexpr size_t SCR_EH   = 496ull << 20;  // blocked 8192x256 f16 = 4 MiB
constexpr size_t SCR_EL   = 500ull << 20;
constexpr size_t SCR_ZZ   = 504ull << 20;               // 16384 f32
constexpr size_t SCR_R    = (504ull << 20) + 65536;     // 16384 f32 cross-bound
constexpr size_t SCR_GMIN = (504ull << 20) + 131072;    // 16384 u32 global approx min
constexpr size_t SCR_WCNT = (504ull << 20) + 196608;    // 16384 u32 per-row counts
constexpr size_t SCR_KEY  = 505ull << 20;  // 16384 u64
constexpr size_t SCR_PART = 506ull << 20;  // loss partials f32
constexpr size_t SCR_HIST = 507ull << 20;  // 8192 i32

constexpr int NLOSS_BLOCKS = 2048;
constexpr int CAP = 160;                   // candidates per row (expected ~74)
constexpr float PAD = 1.2e-4f;             // covers 2x ulp(256) rounding chain + margin

constexpr float S_A = 1.0f / 65536.0f;       // 2^-16
constexpr float S_B = 1.0f / 134217728.0f;   // 2^-27

// enc zero-fill: 8192 K2 blocks NT-store 56KB each starting at encb+8.
constexpr size_t ZFILL_PER_BLK = 57344;                       // 14 x 4KB rounds
constexpr size_t TAIL_START    = 8 + 8192ull * ZFILL_PER_BLK; // 469762056
constexpr size_t TAIL_F4       = (536870904ull - TAIL_START) / 16;  // 4194303
}

// Blocked layouts (staging contiguous 16B/lane; LDS conflict-free):
//   A (Z): bytes = tile256*131072 + chunk*16384 + oct*4096 + row*16 + (k&7)*2
//   B (E): bytes = tile128*65536  + chunk*8192  + oct*2048 + col*16 + (k&7)*2

// ---------------- fused split: blocked f16 splits + zz + cross-bound R + inits ----------------
__global__ void vq_split(const float* __restrict__ z, const float* __restrict__ cb,
                         _Float16* __restrict__ ZHb, _Float16* __restrict__ ZLb,
                         _Float16* __restrict__ EHb, _Float16* __restrict__ ELb,
                         float* __restrict__ zz, float* __restrict__ Rr,
                         unsigned long long* __restrict__ keys, int* __restrict__ hist,
                         unsigned* __restrict__ gmin, unsigned* __restrict__ wcnt) {
    __shared__ float tile[64][260];
    __shared__ float sab[32][8];
    int t = threadIdx.x;
    if (blockIdx.x < 512) {
        // ---- Z path: rows n0..n0+31 ----
        int n0 = blockIdx.x * 32;
        int b  = n0 >> 13;
        int d0 = n0 & 8191;
        const float* zb = z + (size_t)b * (C_ * DHW_) + d0;
        int j5 = t & 31, cg8 = t >> 5;          // 8 c-groups
        for (int cc = 0; cc < 256; cc += 8) {
            int c = cc + cg8;
            tile[j5][c] = zb[(size_t)c * DHW_ + j5];   // coalesced over j5
        }
        __syncthreads();
        int tl = n0 >> 8, r0 = n0 & 255;
        float acc = 0.f;                         // Sum(|zh|+|zl|) partial (for R)
        #pragma unroll
        for (int it = 0; it < 4; ++it) {
            int rid = it * 8 + cg8;                    // k-octet 0..31
            half8 h, l;
            #pragma unroll
            for (int e = 0; e < 8; ++e) {
                float v = tile[j5][rid * 8 + e];
                _Float16 hh = (_Float16)v;
                float lf = (v - (float)hh) * 2048.0f;  // residual scaled 2^11
                h[e] = hh;
                l[e] = (_Float16)lf;
                acc += fabsf((float)hh) + fabsf((float)(_Float16)lf);
            }
            size_t off = ((size_t)(tl * 8 + (rid >> 2))) * 8192
                       + (size_t)(rid & 3) * 2048 + (size_t)(r0 + j5) * 8;
            *(half8*)(ZHb + off) = h;
            *(half8*)(ZLb + off) = l;
        }
        sab[j5][cg8] = acc;
        __syncthreads();
        // zz (same per-row math as the passing rounds; only binade matters)
        if (t < 32) {
            float tot[2];
            for (int h2 = 0; h2 < 2; ++h2) {
                float r8[8];
                #pragma unroll
                for (int k = 0; k < 8; ++k) { float x = tile[t][h2*128 + k]; r8[k] = x * x; }
                for (int i = 8; i < 128; i += 8) {
                    #pragma unroll
                    for (int k = 0; k < 8; ++k) { float x = tile[t][h2*128 + i + k]; r8[k] += x * x; }
                }
                tot[h2] = ((r8[0]+r8[1]) + (r8[2]+r8[3])) + ((r8[4]+r8[5]) + (r8[6]+r8[7]));
            }
            zz[n0 + t] = tot[0] + tot[1];
            float s = 0.f;
            #pragma unroll
            for (int gq = 0; gq < 8; ++gq) s += sab[t][gq];
            // hard bound on 2*S_B*|cross|: |eh|<=8.004, |el|<=8  -> 8.01 covers
            Rr[n0 + t] = s * (2.0f * 8.01f / 134217728.0f);
        }
        if (blockIdx.x < 64) keys[blockIdx.x * 256 + t] = ~0ull;
        else if (blockIdx.x < 96) hist[(blockIdx.x - 64) * 256 + t] = 0;
        else if (blockIdx.x < 160) gmin[(blockIdx.x - 96) * 256 + t] = 0xFFFFFFFFu;
        else if (blockIdx.x < 224) wcnt[(blockIdx.x - 160) * 256 + t] = 0u;
    } else {
        // ---- E path: codebook rows j0..j0+63, pre-scaled by 2^16 (exact) ----
        int j = t & 63, grp = t >> 6;
        int j0 = (blockIdx.x - 512) * 64;
        for (int i = 0; i < 64; ++i)
            tile[i][t] = cb[(size_t)(j0 + i) * K_ + t] * 65536.0f;   // coalesced over t
        __syncthreads();
        int tl = j0 >> 7, r0 = j0 & 127;
        #pragma unroll
        for (int it = 0; it < 8; ++it) {
            int rid = it * 4 + grp;
            half8 h, l;
            #pragma unroll
            for (int e = 0; e < 8; ++e) {
                float v = tile[j][rid * 8 + e];
                _Float16 hh = (_Float16)v;
                h[e] = hh;
                l[e] = (_Float16)((v - (float)hh) * 2048.0f);
            }
            size_t off = ((size_t)(tl * 8 + (rid >> 2))) * 4096
                       + (size_t)(rid & 3) * 1024 + (size_t)(r0 + j) * 8;
            *(half8*)(EHb + off) = h;
            *(half8*)(ELb + off) = l;
        }
    }
}

// ---------------- K2: pass-A GEMM -> gmin + candidate push + zfill ----------------
// TM=TN=128, KC=32, 8 chunks, 4 waves (2x2), 2 bufs x 16KB (ZH+EH) -> 4 blocks/CU.
// Epilogue: block-local rowmin; atomicMin gmin; push (da,j) for
// da <= min(gmin_racy, Lb) + W.  gmin race is stale-safe (monotone decreasing,
// stale = larger = superset); winner always pushed since Lb >= gmin_final.

DEVI void stage_chunk(const char* zh, const char* eh, char* b, int t, int c) {
    #pragma unroll
    for (int i = 0; i < 2; ++i) {
        int f = i * 256 + t;                       // 0..511 = oct*128 + row
        int ao = (f >> 7) * 4096 + (f & 127) * 16;
        GLL(zh + (size_t)c * 16384 + ao, b + f * 16);
    }
    #pragma unroll
    for (int i = 0; i < 2; ++i) {
        int f = i * 256 + t;
        int eo = (f >> 7) * 2048 + (f & 127) * 16;
        GLL(eh + (size_t)c * 8192 + eo, b + 8192 + f * 16);
    }
}

DEVI void zfill2(char* zb, int t, int r0) {
    floatx4 z4 = {0.f, 0.f, 0.f, 0.f};
    __builtin_nontemporal_store(z4, (floatx4*)(zb + (size_t)r0 * 4096 + t * 16));
    __builtin_nontemporal_store(z4, (floatx4*)(zb + (size_t)(r0 + 1) * 4096 + t * 16));
}

DEVI void compute_chunk(const char* b, int wm, int wn, int rr,
                        floatx4 (&acc)[4][4]) {
    const char* Ab = b;
    const char* Bb = b + 8192;
    half8 azh[4], beh[4];
    #pragma unroll
    for (int f = 0; f < 4; ++f) {
        int row = wm * 64 + f * 16 + rr;
        azh[f] = *(const half8*)(Ab + row * 16);
        int col = wn * 64 + f * 16 + rr;
        beh[f] = *(const half8*)(Bb + col * 16);
    }
    __builtin_amdgcn_s_setprio(1);
    #pragma unroll
    for (int fi = 0; fi < 4; ++fi)
        #pragma unroll
        for (int fj = 0; fj < 4; ++fj)
            acc[fi][fj] = MFMA16(azh[fi], beh[fj], acc[fi][fj]);
    __builtin_amdgcn_s_setprio(0);
}

__launch_bounds__(256, 4)
__global__ void vq_gemm1(const _Float16* __restrict__ ZHb, const _Float16* __restrict__ EHb,
                         const float* __restrict__ zz, const float* __restrict__ Rr,
                         unsigned* __restrict__ gmin, unsigned* __restrict__ wcnt,
                         unsigned long long* __restrict__ cand,
                         char* __restrict__ zfill) {
    __shared__ _Float16 lds[2][8192];                 // 2 x 16KB (ZH+EH only)
    __shared__ unsigned rowminu[128];

    int orig = blockIdx.x;
    int xcd = orig & 7;
    int loc = orig >> 3;                 // 0..1023
    int bm = xcd * 16 + (loc & 15);      // 0..127 (128-row Z slices)
    int bn = loc >> 4;                   // 0..63  (128-row E tiles)
    int m0 = bm * 128, n0v = bn * 128;

    int t = threadIdx.x;
    int lane = t & 63, wid = t >> 6;
    int wm = wid >> 1, wn = wid & 1;     // 2x2 waves of 64x64
    int g = lane >> 4, rr = lane & 15;

    const char* zh = (const char*)ZHb + (size_t)(bm >> 1) * 131072 + (size_t)(bm & 1) * 2048;
    const char* eh = (const char*)EHb + (size_t)bn * 65536;
    char* zb = zfill + (size_t)orig * ZFILL_PER_BLK;

    floatx4 acc[4][4];
    #pragma unroll
    for (int i = 0; i < 4; ++i)
        #pragma unroll
        for (int jj = 0; jj < 4; ++jj)
            acc[i][jj] = (floatx4){0.f, 0.f, 0.f, 0.f};

    char* L0 = (char*)lds[0];
    char* L1 = (char*)lds[1];
    char* L0g = L0 + g * 2048;
    char* L1g = L1 + g * 2048;

    stage_chunk(zh, eh, L0, t, 0);
    VM0; BAR;
    stage_chunk(zh, eh, L1, t, 1); zfill2(zb, t, 0);  compute_chunk(L0g, wm, wn, rr, acc); VM0; BAR;
    stage_chunk(zh, eh, L0, t, 2); zfill2(zb, t, 2);  compute_chunk(L1g, wm, wn, rr, acc); VM0; BAR;
    stage_chunk(zh, eh, L1, t, 3); zfill2(zb, t, 4);  compute_chunk(L0g, wm, wn, rr, acc); VM0; BAR;
    stage_chunk(zh, eh, L0, t, 4); zfill2(zb, t, 6);  compute_chunk(L1g, wm, wn, rr, acc); VM0; BAR;
    stage_chunk(zh, eh, L1, t, 5); zfill2(zb, t, 8);  compute_chunk(L0g, wm, wn, rr, acc); VM0; BAR;
    stage_chunk(zh, eh, L0, t, 6); zfill2(zb, t, 10); compute_chunk(L1g, wm, wn, rr, acc); VM0; BAR;
    stage_chunk(zh, eh, L1, t, 7); zfill2(zb, t, 12); compute_chunk(L0g, wm, wn, rr, acc); VM0; BAR;
    compute_chunk(L1g, wm, wn, rr, acc);

    if (t < 128) rowminu[t] = 0xFFFFFFFFu;
    __syncthreads();
    #pragma unroll
    for (int fi = 0; fi < 4; ++fi) {
        #pragma unroll
        for (int r = 0; r < 4; ++r) {
            int rowl = wm * 64 + fi * 16 + g * 4 + r;
            float zzv = zz[m0 + rowl];
            unsigned best = 0xFFFFFFFFu;
            #pragma unroll
            for (int fj = 0; fj < 4; ++fj) {
                float d = zzv - 2.0f * (acc[fi][fj][r] * S_A);   // approx (pass-A), d>0
                unsigned db = __float_as_uint(d);
                if (db < best) best = db;
            }
            #pragma unroll
            for (int s = 1; s < 16; s <<= 1) {
                unsigned o = __shfl_xor(best, s, 64);
                if (o < best) best = o;
            }
            if (rr == 0) atomicMin(&rowminu[rowl], best);
        }
    }
    __syncthreads();
    if (t < 128) atomicMin(&gmin[m0 + t], rowminu[t]);   // publish early (helps later blocks)
    __syncthreads();

    // ---- push candidates ----
    #pragma unroll
    for (int fi = 0; fi < 4; ++fi) {
        #pragma unroll
        for (int r = 0; r < 4; ++r) {
            int rowl = wm * 64 + fi * 16 + g * 4 + r;
            int rowg = m0 + rowl;
            float zzv = zz[rowg];
            unsigned gm = gmin[rowg];            // racy-monotone, stale-safe
            unsigned lb = rowminu[rowl];
            float thr = __uint_as_float(gm < lb ? gm : lb) + 2.0f * Rr[rowg] + PAD;
            #pragma unroll
            for (int fj = 0; fj < 4; ++fj) {
                float da = zzv - 2.0f * (acc[fi][fj][r] * S_A);
                if (da <= thr) {
                    unsigned slot = atomicAdd(&wcnt[rowg], 1u);
                    if (slot < (unsigned)CAP)
                        cand[(size_t)rowg * CAP + slot] =
                            ((unsigned long long)__float_as_uint(da) << 32)
                          | (unsigned)(n0v + wn * 64 + fj * 16 + rr);
                }
            }
        }
    }
}

// ---------------- K3: candidate-list exact refine (one wave per row) ----------------

DEVI float dot8f(half8 a, half8 b, float c) {
#if __has_builtin(__builtin_amdgcn_fdot2)
    const half2v* pa = (const half2v*)&a;
    const half2v* pb = (const half2v*)&b;
    c = __builtin_amdgcn_fdot2(pa[0], pb[0], c, false);
    c = __builtin_amdgcn_fdot2(pa[1], pb[1], c, false);
    c = __builtin_amdgcn_fdot2(pa[2], pb[2], c, false);
    c = __builtin_amdgcn_fdot2(pa[3], pb[3], c, false);
#else
    #pragma unroll
    for (int q = 0; q < 8; ++q) c += (float)a[q] * (float)b[q];
#endif
    return c;
}

// wave-parallel exact eval of column j (global), returns key on lane 0
DEVI unsigned long long exact_eval(const char* zhr, const char* zlr,
                                   const _Float16* EHb, const _Float16* ELb,
                                   int j, float zzv, int lane) {
    int bnj = j >> 7, jc = j & 127;
    int oc = lane & 31;
    size_t ao = (size_t)(oc >> 2) * 16384 + (size_t)(oc & 3) * 4096;
    size_t eo = (size_t)(oc >> 2) * 8192 + (size_t)(oc & 3) * 2048;
    const char* ecc = (const char*)EHb + (size_t)bnj * 65536 + (size_t)jc * 16;
    const char* elc = (const char*)ELb + (size_t)bnj * 65536 + (size_t)jc * 16;
    half8 zh8 = *(const half8*)(zhr + ao);
    half8 eh8 = *(const half8*)(ecc + eo);
    float part = 0.f;
    if (lane < 32) {
        #pragma unroll
        for (int q = 0; q < 8; ++q)
            part += (float)zh8[q] * (float)eh8[q];
    } else {
        half8 zl8 = *(const half8*)(zlr + ao);
        half8 el8 = *(const half8*)(elc + eo);
        #pragma unroll
        for (int q = 0; q < 8; ++q)
            part += (float)zl8[q] * (float)eh8[q] + (float)zh8[q] * (float)el8[q];
    }
    #pragma unroll
    for (int s = 1; s < 32; s <<= 1) part += __shfl_xor(part, s, 64);
    float other = __shfl_xor(part, 32, 64);
    float dot = part * S_A + other * S_B;   // ah*S_A + cross*S_B (lane0 correct)
    float d = zzv - 2.0f * dot;
    return ((unsigned long long)__float_as_uint(d) << 32) | (unsigned)j;
}

__launch_bounds__(256, 4)
__global__ void vq_refine(const _Float16* __restrict__ ZHb, const _Float16* __restrict__ ZLb,
                          const _Float16* __restrict__ EHb, const _Float16* __restrict__ ELb,
                          const float* __restrict__ zz, const float* __restrict__ Rr,
                          const unsigned* __restrict__ gmin,
                          const unsigned long long* __restrict__ cand,
                          const unsigned* __restrict__ wcnt,
                          unsigned long long* __restrict__ keys) {
    int t = threadIdx.x;
    int lane = t & 63;
    int gw = blockIdx.x * 4 + (t >> 6);     // 8192 waves
    for (int row = gw; row < N_; row += 8192) {
        int nc = (int)wcnt[row];
        const char* zhr = (const char*)ZHb + (size_t)(row >> 8) * 131072 + (size_t)(row & 255) * 16;
        const char* zlr = (const char*)ZLb + (size_t)(row >> 8) * 131072 + (size_t)(row & 255) * 16;
        float zzv = zz[row];
        float thr = __uint_as_float(gmin[row]) + 2.0f * Rr[row] + PAD;
        if (nc > 0 && nc <= CAP) {
            unsigned long long bestkey = ~0ull;     // lane 0's running min
            for (int base = 0; base < nc; base += 64) {
                int ci = base + lane;
                unsigned long long cv = (ci < nc) ? cand[(size_t)row * CAP + ci] : ~0ull;
                float da = __uint_as_float((unsigned)(cv >> 32));
                bool surv = (ci < nc) && (da <= thr);
                unsigned long long mask = __ballot(surv);
                while (mask) {
                    int b = __ffsll((unsigned long long)mask) - 1;
                    mask &= mask - 1;
                    unsigned long long cvb = __shfl(cv, b, 64);
                    int j = (int)(unsigned)(cvb & 0xFFFFFFFFull);
                    unsigned long long key = exact_eval(zhr, zlr, EHb, ELb, j, zzv, lane);
                    if (lane == 0 && key < bestkey) bestkey = key;
                }
            }
            if (lane == 0) atomicMin(&keys[row], bestkey);
        } else {
            // fallback (overflow / empty — ~never): full scan with approx filter
            for (int bn = 0; bn < 64; ++bn) {
                const char* ehb = (const char*)EHb + (size_t)bn * 65536;
                #pragma unroll
                for (int half = 0; half < 2; ++half) {
                    int j = half * 64 + lane;
                    const char* ehc = ehb + (size_t)j * 16;
                    float acc = 0.f;
                    #pragma unroll
                    for (int oc = 0; oc < 32; ++oc) {
                        size_t ao = (size_t)(oc >> 2) * 16384 + (size_t)(oc & 3) * 4096;
                        size_t eo = (size_t)(oc >> 2) * 8192 + (size_t)(oc & 3) * 2048;
                        half8 zh8 = *(const half8*)(zhr + ao);
                        half8 eh8 = *(const half8*)(ehc + eo);
                        acc = dot8f(zh8, eh8, acc);
                    }
                    float da = zzv - 2.0f * (acc * S_A);
                    unsigned long long mask = __ballot(da <= thr);
                    while (mask) {
                        int b = __ffsll((unsigned long long)mask) - 1;
                        mask &= mask - 1;
                        int jg = bn * 128 + half * 64 + b;
                        unsigned long long key = exact_eval(zhr, zlr, EHb, ELb, jg, zzv, lane);
                        if (lane == 0) atomicMin(&keys[row], key);
                    }
                }
            }
        }
    }
}

// ---------------- z_q + loss partials + idx output + histogram (fused) ----------------
__global__ void vq_zq_loss(const float* __restrict__ z, const float* __restrict__ cb,
                           const unsigned long long* __restrict__ keys,
                           float* __restrict__ out0, float* __restrict__ parts,
                           float* __restrict__ out_idx, int* __restrict__ hist) {
    size_t i0 = ((size_t)blockIdx.x * 256 + threadIdx.x) * 8;
    int c   = (int)((i0 >> 13) & 255);
    int b   = (int)(i0 >> 21);
    int dhw = (int)(i0 & 8191);
    int nb  = b * DHW_ + dhw;
    int jj[8];
    #pragma unroll
    for (int e = 0; e < 8; ++e)
        jj[e] = (int)(unsigned)(keys[nb + e] & 0xFFFFFFFFull);
    float ls = 0.f;
    #pragma unroll
    for (int e = 0; e < 8; ++e) {
        float zq = cb[(size_t)jj[e] * K_ + c];
        float zt = z[i0 + e];
        float diff = zq - zt;        // fl, matches ref
        out0[i0 + e] = zt + diff;    // fl(z_t + fl(z_q - z_t))
        ls += diff * diff;
    }
    if (c == 0) {
        #pragma unroll
        for (int e = 0; e < 8; ++e) {
            out_idx[nb + e] = (float)jj[e];
            atomicAdd(&hist[jj[e]], 1);
        }
    }
    __shared__ float red[256];
    red[threadIdx.x] = ls;
    __syncthreads();
    for (int s = 128; s > 0; s >>= 1) {
        if (threadIdx.x < (unsigned)s) red[threadIdx.x] += red[threadIdx.x + s];
        __syncthreads();
    }
    if (threadIdx.x == 0) parts[blockIdx.x] = red[0];
}

// ---------------- loss + perplexity ----------------
__global__ void vq_finalize_scalars(const float* __restrict__ parts,
                                    const int* __restrict__ hist,
                                    float* __restrict__ out) {
    __shared__ double dred[256];
    int t = threadIdx.x;
    double ent = 0.0;
    for (int i = t; i < NE_; i += 256) {
        float em = (float)hist[i] * (1.0f / 16384.0f);   // exact (pow2)
        float term = em * logf(em + 1e-10f);
        ent += (double)term;
    }
    dred[t] = ent;
    __syncthreads();
    for (int s = 128; s > 0; s >>= 1) {
        if (t < s) dred[t] += dred[t + s];
        __syncthreads();
    }
    double entr = 0.0;
    if (t == 0) entr = dred[0];
    __syncthreads();
    double ls = 0.0;
    for (int i = t; i < NLOSS_BLOCKS; i += 256) ls += (double)parts[i];
    dred[t] = ls;
    __syncthreads();
    for (int s = 128; s > 0; s >>= 1) {
        if (t < s) dred[t] += dred[t + s];
        __syncthreads();
    }
    if (t == 0) {
        double m = dred[0] / 4194304.0;
        float m1 = (float)m;
        out[LOSS_OFF] = m1 + 0.25f * m1;
        out[PERP_OFF] = (float)exp(-entr);
    }
}

// ---------------- zero the scratch tail + head/tail slivers of enc ----------------
__global__ void vq_zero_tail(char* __restrict__ encb) {
    size_t i = (size_t)blockIdx.x * 256 + threadIdx.x;
    floatx4 z4 = {0.f, 0.f, 0.f, 0.f};
    char* base = encb + TAIL_START;
    for (size_t k = i; k < TAIL_F4; k += 131072)
        *(floatx4*)(base + k * 16) = z4;
    if (i == 0) {
        float2 z2 = {0.f, 0.f};
        *(float2*)encb = z2;                      // enc[0..1]
        *(float2*)(encb + 536870904ull) = z2;     // enc[last two]
    }
}

// ---------------- place the ones ----------------
__global__ void vq_write_ones(const float* __restrict__ idxf, float* __restrict__ enc) {
    int n = blockIdx.x * 256 + threadIdx.x;
    enc[(size_t)n * NE_ + (int)idxf[n]] = 1.0f;
}

extern "C" void kernel_launch(void* const* d_in, const int* in_sizes, int n_in,
                              void* d_out, int out_size, void* d_ws, size_t ws_size,
                              hipStream_t stream) {
    const float* z  = (const float*)d_in[0];
    const float* cb = (const float*)d_in[1];
    float* out = (float*)d_out;

    // 256B-aligned scratch base inside the enc-region tail
    char* scr = (char*)(((uintptr_t)(out + ENC_OFF) + 255) & ~(uintptr_t)255);
    _Float16* ZHb = (_Float16*)(scr + SCR_ZH);
    _Float16* ZLb = (_Float16*)(scr + SCR_ZL);
    _Float16* EHb = (_Float16*)(scr + SCR_EH);
    _Float16* ELb = (_Float16*)(scr + SCR_EL);
    float* zz = (float*)(scr + SCR_ZZ);
    float* Rr = (float*)(scr + SCR_R);
    unsigned* gmin = (unsigned*)(scr + SCR_GMIN);
    unsigned* wcnt = (unsigned*)(scr + SCR_WCNT);
    unsigned long long* cand = (unsigned long long*)(scr + SCR_CAND);
    unsigned long long* keys = (unsigned long long*)(scr + SCR_KEY);
    float* parts = (float*)(scr + SCR_PART);
    int* hist = (int*)(scr + SCR_HIST);
    float* out_idx = out + IDX_OFF;
    float* enc = out + ENC_OFF;
    char* encb = (char*)enc;

    vq_split<<<640, 256, 0, stream>>>(z, cb, ZHb, ZLb, EHb, ELb, zz, Rr, keys, hist, gmin, wcnt);
    vq_gemm1<<<8192, 256, 0, stream>>>(ZHb, EHb, zz, Rr, gmin, wcnt, cand, encb + 8);
    vq_refine<<<2048, 256, 0, stream>>>(ZHb, ZLb, EHb, ELb, zz, Rr, gmin, cand, wcnt, keys);
    vq_zq_loss<<<NLOSS_BLOCKS, 256, 0, stream>>>(z, cb, keys, out, parts, out_idx, hist);
    vq_finalize_scalars<<<1, 256, 0, stream>>>(parts, hist, out);
    vq_zero_tail<<<512, 256, 0, stream>>>(encb);
    vq_write_ones<<<64, 256, 0, stream>>>(out_idx, enc);
}